// Round 1
// baseline (416.112 us; speedup 1.0000x reference)
//
#include <hip/hip_runtime.h>

#define N_NODES 20000
#define N_EDGES 50000
#define NPB 8   // nodes per block in the fused conv kernel

// ---------------- histogram of dst ----------------
__global__ __launch_bounds__(256) void k_hist(const int* __restrict__ ei, int* __restrict__ cnt) {
    int e = blockIdx.x * 256 + threadIdx.x;
    if (e < N_EDGES) atomicAdd(&cnt[ei[N_EDGES + e]], 1);
}

// ---------------- exclusive scan over 20000 counts (single block) ----------------
__global__ __launch_bounds__(1024) void k_scan(const int* __restrict__ cnt, int* __restrict__ off,
                                               int* __restrict__ cursor, float* __restrict__ cntf) {
    __shared__ int s[1024];
    __shared__ int base;
    int tid = threadIdx.x;
    if (tid == 0) base = 0;
    __syncthreads();
    const int NCH = (N_NODES + 1023) / 1024;
    for (int c = 0; c < NCH; c++) {
        int n = c * 1024 + tid;
        int v = (n < N_NODES) ? cnt[n] : 0;
        s[tid] = v;
        __syncthreads();
        for (int d = 1; d < 1024; d <<= 1) {
            int t = (tid >= d) ? s[tid - d] : 0;
            __syncthreads();
            s[tid] += t;
            __syncthreads();
        }
        int incl = s[tid];
        int excl = incl - v;
        if (n < N_NODES) {
            int o = base + excl;
            off[n] = o;
            cursor[n] = o;
            cntf[n] = v > 0 ? (float)v : 1.0f;
        }
        __syncthreads();
        if (tid == 1023) base += incl;
        __syncthreads();
    }
    if (tid == 0) off[N_NODES] = base;
}

// ---------------- scatter edge ids grouped by dst ----------------
__global__ __launch_bounds__(256) void k_scatter(const int* __restrict__ ei, int* __restrict__ cursor,
                                                 int* __restrict__ eord) {
    int e = blockIdx.x * 256 + threadIdx.x;
    if (e < N_EDGES) {
        int d = ei[N_EDGES + e];
        int p = atomicAdd(&cursor[d], 1);
        eord[p] = e;
    }
}

// ---------------- X0 = relu(h @ lin0_w + lin0_b) ----------------
__global__ __launch_bounds__(256) void k_lin0(const float* __restrict__ h, const float* __restrict__ w,
                                              const float* __restrict__ b, float* __restrict__ X0) {
    __shared__ float hr[NPB][64];
    int tid = threadIdx.x;
    int n0 = blockIdx.x * NPB;
    for (int i = tid; i < NPB * 64; i += 256) hr[i >> 6][i & 63] = h[n0 * 64 + i];
    __syncthreads();
    int g = tid & 63, q = tid >> 6;
    for (int j = 0; j < 2; j++) {
        int i = q * 2 + j;
        float acc = b[g];
        for (int f = 0; f < 64; f++) acc += hr[i][f] * w[f * 64 + g];
        X0[(n0 + i) * 64 + g] = acc > 0.f ? acc : 0.f;
    }
}

// ---------------- per-edge t[e,16] = relu(relu(edge_attr@short)@nn1) ----------------
__global__ __launch_bounds__(256) void k_edge_t(const float* __restrict__ eattr,
                                                const float* __restrict__ sw, const float* __restrict__ sb,
                                                const float* __restrict__ w1, const float* __restrict__ b1,
                                                float* __restrict__ t_arr) {
    __shared__ float ea[4][64];
    int tid = threadIdx.x;
    int l = tid & 63, q = tid >> 6;
    int e = blockIdx.x * 4 + q;
    float a0 = eattr[e * 5 + 0], a1 = eattr[e * 5 + 1], a2 = eattr[e * 5 + 2],
          a3 = eattr[e * 5 + 3], a4 = eattr[e * 5 + 4];
    float v = sb[l] + a0 * sw[l] + a1 * sw[64 + l] + a2 * sw[128 + l] + a3 * sw[192 + l] + a4 * sw[256 + l];
    ea[q][l] = v > 0.f ? v : 0.f;
    __syncthreads();
    if (l < 16) {
        float acc = b1[l];
        for (int c = 0; c < 64; c++) acc += ea[q][c] * w1[c * 16 + l];
        t_arr[e * 16 + l] = acc > 0.f ? acc : 0.f;
    }
}

// ---------------- fused conv + GRU, one iteration ----------------
// agg[n,g] = (1/cnt) [ sum_kf S[n][kf]*nn2w[kf*64+g] + sum_f Sx[n][f]*nn2b[f*64+g] ]
// m = relu(agg + Xprev@rootw + convb);  Xout = GRU(m, Xprev)
__global__ __launch_bounds__(256) void k_conv(
    const float* __restrict__ Xprev, float* __restrict__ Xout,
    const float* __restrict__ t_arr, const int* __restrict__ eord,
    const int* __restrict__ off, const float* __restrict__ cntf,
    const int* __restrict__ ei,
    const float* __restrict__ nn2w, const float* __restrict__ nn2b,
    const float* __restrict__ rootw, const float* __restrict__ convb,
    const float* __restrict__ wih, const float* __restrict__ whh,
    const float* __restrict__ bih, const float* __restrict__ bhh) {
    __shared__ float S[NPB][1088];   // [16][64] outer-product sums + [64] Sx at 1024..
    __shared__ float XR[NPB][64];    // own rows of Xprev (== hidden)
    __shared__ float M[NPB][64];     // relu(conv) output
    int tid = threadIdx.x;
    int lane = tid & 63;
    int wq = tid >> 6;               // wave id 0..3
    int n0 = blockIdx.x * NPB;

    for (int i = tid; i < NPB * 64; i += 256) XR[i >> 6][i & 63] = Xprev[n0 * 64 + i];

    // ---- S accumulation: wave wq handles nodes 2wq, 2wq+1; lane = f ----
    for (int j = 0; j < 2; j++) {
        int i = wq * 2 + j;
        int n = n0 + i;
        float acc[16];
#pragma unroll
        for (int k = 0; k < 16; k++) acc[k] = 0.f;
        float sx = 0.f;
        int e0 = off[n], e1 = off[n + 1];
        for (int p = e0; p < e1; p++) {
            int e = eord[p];
            int s = ei[e];                       // src
            float x = Xprev[s * 64 + lane];
            const float* tp = &t_arr[e * 16];
#pragma unroll
            for (int k = 0; k < 16; k++) acc[k] += tp[k] * x;
            sx += x;
        }
#pragma unroll
        for (int k = 0; k < 16; k++) S[i][k * 64 + lane] = acc[k];
        S[i][1024 + lane] = sx;
    }
    __syncthreads();

    // ---- contraction [1088] -> [64] ; wave wq computes nodes 2wq, 2wq+1, lane = g ----
    int g = lane;
    float a0 = 0.f, a1 = 0.f;
    const float* S0 = S[wq * 2 + 0];
    const float* S1 = S[wq * 2 + 1];
#pragma unroll 8
    for (int kf = 0; kf < 1024; kf++) {
        float wv = nn2w[kf * 64 + g];
        a0 += S0[kf] * wv;
        a1 += S1[kf] * wv;
    }
#pragma unroll 8
    for (int f = 0; f < 64; f++) {
        float bv = nn2b[f * 64 + g];
        a0 += S0[1024 + f] * bv;
        a1 += S1[1024 + f] * bv;
    }

    float cb = convb[g];
    float aggs[2] = {a0, a1};
    for (int j = 0; j < 2; j++) {
        int i = wq * 2 + j;
        int n = n0 + i;
        float acc = aggs[j] / cntf[n] + cb;
        for (int f = 0; f < 64; f++) acc += XR[i][f] * rootw[f * 64 + g];
        M[i][g] = acc > 0.f ? acc : 0.f;
    }
    __syncthreads();

    // ---- GRU cell ----
    for (int j = 0; j < 2; j++) {
        int i = wq * 2 + j;
        int n = n0 + i;
        float Gr = bih[g], Gz = bih[64 + g], Gn = bih[128 + g];
        float Hr = bhh[g], Hz = bhh[64 + g], Hn = bhh[128 + g];
        for (int f = 0; f < 64; f++) {
            float mv = M[i][f], hv = XR[i][f];
            Gr += mv * wih[f * 192 + g];        Hr += hv * whh[f * 192 + g];
            Gz += mv * wih[f * 192 + 64 + g];   Hz += hv * whh[f * 192 + 64 + g];
            Gn += mv * wih[f * 192 + 128 + g];  Hn += hv * whh[f * 192 + 128 + g];
        }
        float r = 1.f / (1.f + __expf(-(Gr + Hr)));
        float z = 1.f / (1.f + __expf(-(Gz + Hz)));
        float nt = tanhf(Gn + r * Hn);
        Xout[n * 64 + g] = (1.f - z) * nt + z * XR[i][g];
    }
}

extern "C" void kernel_launch(void* const* d_in, const int* in_sizes, int n_in,
                              void* d_out, int out_size, void* d_ws, size_t ws_size,
                              hipStream_t stream) {
    const float* h     = (const float*)d_in[0];
    const int*   ei    = (const int*)d_in[1];    // [2, E]: row0 = src, row1 = dst
    // d_in[2] edge_weight: unused by the reference
    const float* eattr = (const float*)d_in[3];
    const float* lin0w = (const float*)d_in[4];
    const float* lin0b = (const float*)d_in[5];
    const float* shw   = (const float*)d_in[6];
    const float* shb   = (const float*)d_in[7];
    const float* w1    = (const float*)d_in[8];
    const float* b1    = (const float*)d_in[9];
    const float* w2    = (const float*)d_in[10];
    const float* b2    = (const float*)d_in[11];
    const float* rootw = (const float*)d_in[12];
    const float* convb = (const float*)d_in[13];
    const float* wih   = (const float*)d_in[14];
    const float* whh   = (const float*)d_in[15];
    const float* bih   = (const float*)d_in[16];
    const float* bhh   = (const float*)d_in[17];

    char* ws = (char*)d_ws;
    float* X0    = (float*)ws; ws += (size_t)N_NODES * 64 * 4;
    float* X1    = (float*)ws; ws += (size_t)N_NODES * 64 * 4;
    float* t_arr = (float*)ws; ws += (size_t)N_EDGES * 16 * 4;
    int*   cnt   = (int*)ws;   ws += (size_t)N_NODES * 4;
    int*   off   = (int*)ws;   ws += (size_t)(N_NODES + 1) * 4;
    int*   cursor= (int*)ws;   ws += (size_t)N_NODES * 4;
    float* cntf  = (float*)ws; ws += (size_t)N_NODES * 4;
    int*   eord  = (int*)ws;   ws += (size_t)N_EDGES * 4;

    hipMemsetAsync(cnt, 0, N_NODES * 4, stream);
    k_hist<<<(N_EDGES + 255) / 256, 256, 0, stream>>>(ei, cnt);
    k_scan<<<1, 1024, 0, stream>>>(cnt, off, cursor, cntf);
    k_scatter<<<(N_EDGES + 255) / 256, 256, 0, stream>>>(ei, cursor, eord);
    k_lin0<<<N_NODES / NPB, 256, 0, stream>>>(h, lin0w, lin0b, X0);
    k_edge_t<<<N_EDGES / 4, 256, 0, stream>>>(eattr, shw, shb, w1, b1, t_arr);

    float* out = (float*)d_out;
    k_conv<<<N_NODES / NPB, 256, 0, stream>>>(X0, X1, t_arr, eord, off, cntf, ei,
                                              w2, b2, rootw, convb, wih, whh, bih, bhh);
    k_conv<<<N_NODES / NPB, 256, 0, stream>>>(X1, out, t_arr, eord, off, cntf, ei,
                                              w2, b2, rootw, convb, wih, whh, bih, bhh);
}

// Round 2
// 273.494 us; speedup vs baseline: 1.5215x; 1.5215x over previous
//
#include <hip/hip_runtime.h>

#define N_NODES 20000
#define N_EDGES 50000
#define NPB 8      // nodes per block in the fused conv kernel
#define ROWS 1152  // 1024 (nn2_w) + 64 (nn2_b) + 64 (root_w)
#define RPW 288    // rows per wave (ROWS/4)
#define POFF 0     // partials alias S rows 0..256  (floats 0..2048)
#define MOFF 2048  // M aliases S rows 256..320     (floats 2048..2560)
#define XROFF (1088 * 8)  // XR rows live at S rows 1088..1151

// ---------------- histogram of dst ----------------
__global__ __launch_bounds__(256) void k_hist(const int* __restrict__ ei, int* __restrict__ cnt) {
    int e = blockIdx.x * 256 + threadIdx.x;
    if (e < N_EDGES) atomicAdd(&cnt[ei[N_EDGES + e]], 1);
}

// ---------------- exclusive scan over 20000 counts (single block) ----------------
__global__ __launch_bounds__(1024) void k_scan(const int* __restrict__ cnt, int* __restrict__ off,
                                               int* __restrict__ cursor, float* __restrict__ cntf) {
    __shared__ int s[1024];
    __shared__ int base;
    int tid = threadIdx.x;
    if (tid == 0) base = 0;
    __syncthreads();
    const int NCH = (N_NODES + 1023) / 1024;
    for (int c = 0; c < NCH; c++) {
        int n = c * 1024 + tid;
        int v = (n < N_NODES) ? cnt[n] : 0;
        s[tid] = v;
        __syncthreads();
        for (int d = 1; d < 1024; d <<= 1) {
            int t = (tid >= d) ? s[tid - d] : 0;
            __syncthreads();
            s[tid] += t;
            __syncthreads();
        }
        int incl = s[tid];
        int excl = incl - v;
        if (n < N_NODES) {
            int o = base + excl;
            off[n] = o;
            cursor[n] = o;
            cntf[n] = v > 0 ? (float)v : 1.0f;
        }
        __syncthreads();
        if (tid == 1023) base += incl;
        __syncthreads();
    }
    if (tid == 0) off[N_NODES] = base;
}

// ---------------- scatter edge ids grouped by dst ----------------
__global__ __launch_bounds__(256) void k_scatter(const int* __restrict__ ei, int* __restrict__ cursor,
                                                 int* __restrict__ eord) {
    int e = blockIdx.x * 256 + threadIdx.x;
    if (e < N_EDGES) {
        int d = ei[N_EDGES + e];
        int p = atomicAdd(&cursor[d], 1);
        eord[p] = e;
    }
}

// ---------------- concat [nn2_w ; nn2_b ; root_w] into W2cat[1152][64] ----------------
__global__ __launch_bounds__(256) void k_cat(const float* __restrict__ w2, const float* __restrict__ b2,
                                             const float* __restrict__ rootw, float* __restrict__ W2cat) {
    int idx = blockIdx.x * 256 + threadIdx.x;   // 73728 total
    float v;
    if (idx < 65536) v = w2[idx];
    else if (idx < 69632) v = b2[idx - 65536];
    else v = rootw[idx - 69632];
    W2cat[idx] = v;
}

// ---------------- X0 = relu(h @ lin0_w + lin0_b) ----------------
__global__ __launch_bounds__(256) void k_lin0(const float* __restrict__ h, const float* __restrict__ w,
                                              const float* __restrict__ b, float* __restrict__ X0) {
    __shared__ float hr[NPB][64];
    int tid = threadIdx.x;
    int n0 = blockIdx.x * NPB;
    for (int i = tid; i < NPB * 64; i += 256) hr[i >> 6][i & 63] = h[n0 * 64 + i];
    __syncthreads();
    int g = tid & 63, q = tid >> 6;
    for (int j = 0; j < 2; j++) {
        int i = q * 2 + j;
        float acc = b[g];
        for (int f = 0; f < 64; f++) acc += hr[i][f] * w[f * 64 + g];
        X0[(n0 + i) * 64 + g] = acc > 0.f ? acc : 0.f;
    }
}

// ---------------- per-edge t[e,16] = relu(relu(edge_attr@short)@nn1) ----------------
__global__ __launch_bounds__(256) void k_edge_t(const float* __restrict__ eattr,
                                                const float* __restrict__ sw, const float* __restrict__ sb,
                                                const float* __restrict__ w1, const float* __restrict__ b1,
                                                float* __restrict__ t_arr) {
    __shared__ float ea[4][64];
    int tid = threadIdx.x;
    int l = tid & 63, q = tid >> 6;
    int e = blockIdx.x * 4 + q;
    float a0 = eattr[e * 5 + 0], a1 = eattr[e * 5 + 1], a2 = eattr[e * 5 + 2],
          a3 = eattr[e * 5 + 3], a4 = eattr[e * 5 + 4];
    float v = sb[l] + a0 * sw[l] + a1 * sw[64 + l] + a2 * sw[128 + l] + a3 * sw[192 + l] + a4 * sw[256 + l];
    ea[q][l] = v > 0.f ? v : 0.f;
    __syncthreads();
    if (l < 16) {
        float acc = b1[l];
        for (int c = 0; c < 64; c++) acc += ea[q][c] * w1[c * 16 + l];
        t_arr[e * 16 + l] = acc > 0.f ? acc : 0.f;
    }
}

// ---------------- fused conv + GRU, one iteration ----------------
// S rows (transposed [row][node]): 0..1023  = (1/cnt)*sum_e t[e,k]*x_src[f]   (row k*64+f)
//                                  1024..1087 = (1/cnt)*sum_e x_src[f]        (nn2_b rows)
//                                  1088..1151 = Xprev row f                   (root rows)
// M[i][g] = relu( sum_row S[row][i]*W2cat[row][g] + conv_b[g] );  Xout = GRU(M, Xprev)
__global__ __launch_bounds__(256) void k_conv(
    const float* __restrict__ Xprev, float* __restrict__ Xout,
    const float* __restrict__ t_arr, const int* __restrict__ eord,
    const int* __restrict__ off, const float* __restrict__ cntf,
    const int* __restrict__ ei,
    const float* __restrict__ W2cat, const float* __restrict__ convb,
    const float* __restrict__ wih, const float* __restrict__ whh,
    const float* __restrict__ bih, const float* __restrict__ bhh) {
    __shared__ float S[ROWS * NPB];   // 36864 B; P and M alias dead rows later
    int tid = threadIdx.x;
    int g = tid & 63;                 // lane: feature index
    int wq = tid >> 6;                // wave id 0..3
    int n0 = blockIdx.x * NPB;

    // ---- per-edge accumulation: wave wq owns nodes 2wq, 2wq+1; lane = f ----
    for (int j = 0; j < 2; j++) {
        int i = wq * 2 + j;
        int n = n0 + i;
        float xr = Xprev[n * 64 + g];
        float acc[16];
#pragma unroll
        for (int k = 0; k < 16; k++) acc[k] = 0.f;
        float sx = 0.f;
        int e0 = off[n], e1 = off[n + 1];
        for (int p = e0; p < e1; p++) {
            int e = eord[p];
            int s = ei[e];                       // src
            float x = Xprev[s * 64 + g];
            const float* tp = &t_arr[e * 16];
#pragma unroll
            for (int k = 0; k < 16; k++) acc[k] += tp[k] * x;
            sx += x;
        }
        float ic = 1.0f / cntf[n];
#pragma unroll
        for (int k = 0; k < 16; k++) S[(k * 64 + g) * NPB + i] = acc[k] * ic;
        S[(1024 + g) * NPB + i] = sx * ic;
        S[(1088 + g) * NPB + i] = xr;
    }
    __syncthreads();

    // ---- contraction: wave wq handles rows [wq*288, wq*288+288), 8 node-accumulators ----
    {
        const float* Wp = W2cat + (size_t)(wq * RPW) * 64 + g;
        const float* Sp = S + wq * RPW * NPB;
        float c0 = 0.f, c1 = 0.f, c2 = 0.f, c3 = 0.f, c4 = 0.f, c5 = 0.f, c6 = 0.f, c7 = 0.f;
#pragma unroll 8
        for (int t = 0; t < RPW; t++) {
            float wv = Wp[t * 64];
            float4 sA = *(const float4*)(Sp + t * NPB);
            float4 sB = *(const float4*)(Sp + t * NPB + 4);
            c0 += sA.x * wv; c1 += sA.y * wv; c2 += sA.z * wv; c3 += sA.w * wv;
            c4 += sB.x * wv; c5 += sB.y * wv; c6 += sB.z * wv; c7 += sB.w * wv;
        }
        __syncthreads();   // all S reads done; safe to overwrite rows 0..256 with partials
        float cc[8] = {c0, c1, c2, c3, c4, c5, c6, c7};
#pragma unroll
        for (int i = 0; i < NPB; i++) S[POFF + (i * 64 + g) * 4 + wq] = cc[i];
    }
    __syncthreads();

    // ---- reduce partials + relu -> M (stored [f][node] at MOFF) ----
    {
        float cb = convb[g];
        for (int j = 0; j < 2; j++) {
            int i = wq * 2 + j;
            float4 p = *(const float4*)&S[POFF + (i * 64 + g) * 4];
            float m = p.x + p.y + p.z + p.w + cb;
            S[MOFF + g * NPB + i] = m > 0.f ? m : 0.f;
        }
    }
    __syncthreads();

    // ---- GRU cell: wave wq owns nodes 2wq, 2wq+1 (read M/XR pairs per f) ----
    {
        float Gr0 = bih[g], Gz0 = bih[64 + g], Gn0 = bih[128 + g];
        float Hr0 = bhh[g], Hz0 = bhh[64 + g], Hn0 = bhh[128 + g];
        float Gr1 = Gr0, Gz1 = Gz0, Gn1 = Gn0;
        float Hr1 = Hr0, Hz1 = Hz0, Hn1 = Hn0;
        int ib = wq * 2;
        for (int f = 0; f < 64; f++) {
            float wr = wih[f * 192 + g], wz = wih[f * 192 + 64 + g], wn = wih[f * 192 + 128 + g];
            float ur = whh[f * 192 + g], uz = whh[f * 192 + 64 + g], un = whh[f * 192 + 128 + g];
            float2 mv = *(const float2*)&S[MOFF + f * NPB + ib];
            float2 hv = *(const float2*)&S[XROFF + f * NPB + ib];
            Gr0 += mv.x * wr; Gz0 += mv.x * wz; Gn0 += mv.x * wn;
            Hr0 += hv.x * ur; Hz0 += hv.x * uz; Hn0 += hv.x * un;
            Gr1 += mv.y * wr; Gz1 += mv.y * wz; Gn1 += mv.y * wn;
            Hr1 += hv.y * ur; Hz1 += hv.y * uz; Hn1 += hv.y * un;
        }
        for (int j = 0; j < 2; j++) {
            int i = ib + j;
            int n = n0 + i;
            float gr = j ? Gr1 : Gr0, gz = j ? Gz1 : Gz0, gn = j ? Gn1 : Gn0;
            float hr = j ? Hr1 : Hr0, hz = j ? Hz1 : Hz0, hn = j ? Hn1 : Hn0;
            float r = 1.f / (1.f + __expf(-(gr + hr)));
            float z = 1.f / (1.f + __expf(-(gz + hz)));
            float nt = tanhf(gn + r * hn);
            float xr = S[XROFF + g * NPB + i];
            Xout[n * 64 + g] = (1.f - z) * nt + z * xr;
        }
    }
}

extern "C" void kernel_launch(void* const* d_in, const int* in_sizes, int n_in,
                              void* d_out, int out_size, void* d_ws, size_t ws_size,
                              hipStream_t stream) {
    const float* h     = (const float*)d_in[0];
    const int*   ei    = (const int*)d_in[1];    // [2, E]: row0 = src, row1 = dst
    const float* eattr = (const float*)d_in[3];
    const float* lin0w = (const float*)d_in[4];
    const float* lin0b = (const float*)d_in[5];
    const float* shw   = (const float*)d_in[6];
    const float* shb   = (const float*)d_in[7];
    const float* w1    = (const float*)d_in[8];
    const float* b1    = (const float*)d_in[9];
    const float* w2    = (const float*)d_in[10];
    const float* b2    = (const float*)d_in[11];
    const float* rootw = (const float*)d_in[12];
    const float* convb = (const float*)d_in[13];
    const float* wih   = (const float*)d_in[14];
    const float* whh   = (const float*)d_in[15];
    const float* bih   = (const float*)d_in[16];
    const float* bhh   = (const float*)d_in[17];

    char* ws = (char*)d_ws;
    float* X0    = (float*)ws; ws += (size_t)N_NODES * 64 * 4;
    float* X1    = (float*)ws; ws += (size_t)N_NODES * 64 * 4;
    float* t_arr = (float*)ws; ws += (size_t)N_EDGES * 16 * 4;
    float* W2cat = (float*)ws; ws += (size_t)ROWS * 64 * 4;
    int*   cnt   = (int*)ws;   ws += (size_t)N_NODES * 4;
    int*   off   = (int*)ws;   ws += (size_t)(N_NODES + 1) * 4;
    int*   cursor= (int*)ws;   ws += (size_t)N_NODES * 4;
    float* cntf  = (float*)ws; ws += (size_t)N_NODES * 4;
    int*   eord  = (int*)ws;   ws += (size_t)N_EDGES * 4;

    hipMemsetAsync(cnt, 0, N_NODES * 4, stream);
    k_hist<<<(N_EDGES + 255) / 256, 256, 0, stream>>>(ei, cnt);
    k_scan<<<1, 1024, 0, stream>>>(cnt, off, cursor, cntf);
    k_scatter<<<(N_EDGES + 255) / 256, 256, 0, stream>>>(ei, cursor, eord);
    k_cat<<<(ROWS * 64) / 256, 256, 0, stream>>>(w2, b2, rootw, W2cat);
    k_lin0<<<N_NODES / NPB, 256, 0, stream>>>(h, lin0w, lin0b, X0);
    k_edge_t<<<N_EDGES / 4, 256, 0, stream>>>(eattr, shw, shb, w1, b1, t_arr);

    float* out = (float*)d_out;
    k_conv<<<N_NODES / NPB, 256, 0, stream>>>(X0, X1, t_arr, eord, off, cntf, ei,
                                              W2cat, convb, wih, whh, bih, bhh);
    k_conv<<<N_NODES / NPB, 256, 0, stream>>>(X1, out, t_arr, eord, off, cntf, ei,
                                              W2cat, convb, wih, whh, bih, bhh);
}

// Round 3
// 177.841 us; speedup vs baseline: 2.3398x; 1.5379x over previous
//
#include <hip/hip_runtime.h>

#define N_NODES 20000
#define N_EDGES 50000
#define NPB 16        // nodes per block in k_conv (one MFMA M-tile)
#define NPB0 8        // nodes per block in k_lin0

typedef __attribute__((ext_vector_type(8))) short short8;
typedef __attribute__((ext_vector_type(4))) float f32x4;
typedef unsigned int u32;
typedef unsigned short u16;

// byte-address swizzles (keep ds_read_b128 of strided rows conflict-free)
#define SswzB(i, o) (((i) * 2304 + (o)) ^ (((i) & 7) << 4))   // S: 16 rows x 2304 B
#define MswzB(i, o) (((i) * 256 + (o)) ^ (((i) & 7) << 4))    // M|X: 16 rows x 256 B

__device__ inline u16 f2bf(float x) {            // round-to-nearest-even fp32->bf16
    u32 u = __float_as_uint(x);
    return (u16)((u + 0x7FFFu + ((u >> 16) & 1u)) >> 16);
}

// pack lane-pair (even,odd) bf16 into one dword; even lanes store (avoids
// sub-dword LDS write-merge hazards)
__device__ inline void pack_write(char* base, int byteaddr, float v, int g) {
    u32 m = f2bf(v);
    u32 o = (u32)__shfl_xor((int)m, 1, 64);
    if (!(g & 1)) *(u32*)(base + byteaddr) = (o << 16) | m;
}

// ---------------- histogram of dst ----------------
__global__ __launch_bounds__(256) void k_hist(const int* __restrict__ ei, int* __restrict__ cnt) {
    int e = blockIdx.x * 256 + threadIdx.x;
    if (e < N_EDGES) atomicAdd(&cnt[ei[N_EDGES + e]], 1);
}

// ---------------- exclusive scan over counts (single block, 20/thread) ----------------
__global__ __launch_bounds__(1024) void k_scan(const int* __restrict__ cnt, int* __restrict__ off,
                                               int* __restrict__ cursor, float* __restrict__ cntf) {
    __shared__ int s[1024];
    const int PT = 20;                      // 1024*20 = 20480 >= 20000
    int tid = threadIdx.x;
    int base = tid * PT;
    int loc[PT];
    int sum = 0;
#pragma unroll
    for (int q = 0; q < PT; ++q) {
        int n = base + q;
        int v = (n < N_NODES) ? cnt[n] : 0;
        loc[q] = sum;
        sum += v;
    }
    s[tid] = sum;
    __syncthreads();
    for (int d = 1; d < 1024; d <<= 1) {
        int t = (tid >= d) ? s[tid - d] : 0;
        __syncthreads();
        s[tid] += t;
        __syncthreads();
    }
    int pre = (tid > 0) ? s[tid - 1] : 0;
#pragma unroll
    for (int q = 0; q < PT; ++q) {
        int n = base + q;
        if (n < N_NODES) {
            int o = pre + loc[q];
            int v = ((q + 1 < PT) ? loc[q + 1] : sum) - loc[q];
            off[n] = o;
            cursor[n] = o;
            cntf[n] = v > 0 ? (float)v : 1.0f;
        }
    }
    if (tid == 1023) off[N_NODES] = s[1023];
}

// ---------------- scatter: grouped-by-dst src list + per-edge position ----------------
__global__ __launch_bounds__(256) void k_scatter(const int* __restrict__ ei, int* __restrict__ cursor,
                                                 int* __restrict__ src_ord, int* __restrict__ pos) {
    int e = blockIdx.x * 256 + threadIdx.x;
    if (e < N_EDGES) {
        int d = ei[N_EDGES + e];
        int p = atomicAdd(&cursor[d], 1);
        src_ord[p] = ei[e];
        pos[e] = p;
    }
}

// ---------------- pack weights into MFMA B-fragment layout (bf16) ----------------
// Bp1: [ntile(4)][kb(36)][lane(64)][j(8)] <- W2cat_logical[kb*32+(l>>4)*8+j][nt*16+(l&15)]
//   W2cat rows: 0..1023 nn2_w(kf,g); 1024..1087 nn2_b(f,g); 1088..1151 root_w(f,g)
// Bp2: [ntile(16)][kb(4)][lane(64)][j(8)] <- B2[k2][c], A2=[M|X] (128), cols: r|z|gi_n|gh_n (256)
__global__ __launch_bounds__(256) void k_pack(const float* __restrict__ w2, const float* __restrict__ b2,
                                              const float* __restrict__ rootw,
                                              const float* __restrict__ wih, const float* __restrict__ whh,
                                              u16* __restrict__ Bp1, u16* __restrict__ Bp2) {
    int idx = blockIdx.x * 256 + threadIdx.x;   // 73728 + 32768 total
    if (idx < 73728) {
        int j = idx & 7, l = (idx >> 3) & 63, rest = idx >> 9;
        int kb = rest % 36, nt = rest / 36;
        int row = kb * 32 + (l >> 4) * 8 + j;
        int col = nt * 16 + (l & 15);
        float v;
        if (row < 1024) v = w2[row * 64 + col];
        else if (row < 1088) v = b2[(row - 1024) * 64 + col];
        else v = rootw[(row - 1088) * 64 + col];
        Bp1[idx] = f2bf(v);
    } else {
        int o = idx - 73728;
        int j = o & 7, l = (o >> 3) & 63, rest = o >> 9;
        int kb = rest & 3, nt = rest >> 2;
        int k2 = kb * 32 + (l >> 4) * 8 + j;
        int c = nt * 16 + (l & 15);
        float v;
        if (k2 < 64) {
            v = (c < 192) ? wih[k2 * 192 + c] : 0.f;
        } else {
            int f = k2 - 64;
            v = (c < 128) ? whh[f * 192 + c] : ((c < 192) ? 0.f : whh[f * 192 + c - 64]);
        }
        Bp2[o] = f2bf(v);
    }
}

// ---------------- X0 = relu(h @ lin0_w + lin0_b) ----------------
__global__ __launch_bounds__(256) void k_lin0(const float* __restrict__ h, const float* __restrict__ w,
                                              const float* __restrict__ b, float* __restrict__ X0) {
    __shared__ float hr[NPB0][64];
    int tid = threadIdx.x;
    int n0 = blockIdx.x * NPB0;
    for (int i = tid; i < NPB0 * 64; i += 256) hr[i >> 6][i & 63] = h[n0 * 64 + i];
    __syncthreads();
    int g = tid & 63, q = tid >> 6;
    for (int j = 0; j < 2; j++) {
        int i = q * 2 + j;
        float acc = b[g];
        for (int f = 0; f < 64; f++) acc += hr[i][f] * w[f * 64 + g];
        X0[(n0 + i) * 64 + g] = acc > 0.f ? acc : 0.f;
    }
}

// ---------------- per-edge t (bf16), written at its sorted position ----------------
__global__ __launch_bounds__(256) void k_edge_t(const float* __restrict__ eattr,
                                                const float* __restrict__ sw, const float* __restrict__ sb,
                                                const float* __restrict__ w1, const float* __restrict__ b1,
                                                const int* __restrict__ pos, u16* __restrict__ t_perm) {
    __shared__ float ea[4][64];
    int tid = threadIdx.x;
    int l = tid & 63, q = tid >> 6;
    int e = blockIdx.x * 4 + q;
    float a0 = eattr[e * 5 + 0], a1 = eattr[e * 5 + 1], a2 = eattr[e * 5 + 2],
          a3 = eattr[e * 5 + 3], a4 = eattr[e * 5 + 4];
    float v = sb[l] + a0 * sw[l] + a1 * sw[64 + l] + a2 * sw[128 + l] + a3 * sw[192 + l] + a4 * sw[256 + l];
    ea[q][l] = v > 0.f ? v : 0.f;
    __syncthreads();
    if (l < 16) {
        float acc = b1[l];
        for (int c = 0; c < 64; c++) acc += ea[q][c] * w1[c * 16 + l];
        float t = acc > 0.f ? acc : 0.f;
        t_perm[(size_t)pos[e] * 16 + l] = f2bf(t);
    }
}

// ---------------- fused conv + GRU (MFMA), one iteration ----------------
__global__ __launch_bounds__(256) void k_conv(
    const float* __restrict__ Xprev, float* __restrict__ Xout,
    const u16* __restrict__ t_perm, const int* __restrict__ src_ord,
    const int* __restrict__ off, const float* __restrict__ cntf,
    const u16* __restrict__ Bp1, const u16* __restrict__ Bp2,
    const float* __restrict__ convb,
    const float* __restrict__ bih, const float* __restrict__ bhh) {
    __shared__ __align__(16) char smem[40960];
    char* Sb = smem;                 // S: 16 nodes x 1152 bf16 (swizzled)   [36864 B]
    char* Mb = smem + 36864;         // [M|X]: 16 nodes x 128 bf16 (swizzled) [4096 B]
    float* G = (float*)smem;         // gate sums: 16 x 260 f32, aliases S

    int tid = threadIdx.x;
    int g = tid & 63;
    int wq = tid >> 6;
    int m16 = g & 15, hi4 = g >> 4;
    int n0 = blockIdx.x * NPB;

    // ---- phase 1: per-node edge accumulation -> S (bf16), X -> Mb cols 64..127 ----
    for (int jj = 0; jj < 4; ++jj) {
        int i = wq * 4 + jj;
        int n = n0 + i;
        float xr = Xprev[n * 64 + g];
        float acc[16];
#pragma unroll
        for (int k = 0; k < 16; ++k) acc[k] = 0.f;
        float sx = 0.f;
        int e0 = off[n], e1 = off[n + 1];
        for (int p = e0; p < e1; ++p) {
            int s = src_ord[p];
            float x = Xprev[s * 64 + g];
            const uint4* tp = (const uint4*)(t_perm + (size_t)p * 16);
            uint4 ta = tp[0], tb = tp[1];
            u32 tw[8] = {ta.x, ta.y, ta.z, ta.w, tb.x, tb.y, tb.z, tb.w};
#pragma unroll
            for (int q = 0; q < 8; ++q) {
                acc[2 * q]     += __uint_as_float(tw[q] << 16) * x;
                acc[2 * q + 1] += __uint_as_float(tw[q] & 0xFFFF0000u) * x;
            }
            sx += x;
        }
        float ic = 1.0f / cntf[n];
#pragma unroll
        for (int k = 0; k < 16; ++k)
            pack_write(Sb, SswzB(i, k * 128 + g * 2), acc[k] * ic, g);
        pack_write(Sb, SswzB(i, 2048 + g * 2), sx * ic, g);   // nn2_b rows
        pack_write(Sb, SswzB(i, 2176 + g * 2), xr, g);        // root rows
        pack_write(Mb, MswzB(i, 128 + g * 2), xr, g);         // X half of A2
    }
    __syncthreads();

    // ---- GEMM1: [16 x 1152] @ [1152 x 64] ; wave wq owns feature tile wq ----
    f32x4 d = {0.f, 0.f, 0.f, 0.f};
#pragma unroll
    for (int kb = 0; kb < 36; ++kb) {
        short8 a = *(const short8*)(Sb + SswzB(m16, kb * 64 + hi4 * 16));
        short8 b = *(const short8*)((const char*)Bp1 + ((size_t)(wq * 36 + kb) * 64 + g) * 16);
        d = __builtin_amdgcn_mfma_f32_16x16x32_bf16(a, b, d, 0, 0, 0);
    }
    {
        float cb = convb[wq * 16 + m16];
#pragma unroll
        for (int r = 0; r < 4; ++r) {
            float m = d[r] + cb;
            m = m > 0.f ? m : 0.f;       // relu -> M
            pack_write(Mb, MswzB(hi4 * 4 + r, (wq * 16 + m16) * 2), m, g);
        }
    }
    __syncthreads();   // M complete; all S reads done (G may alias S now)

    // ---- GEMM2: [16 x 128] @ [128 x 256] ; wave wq owns gate wq (cols 64wq..) ----
    short8 a2[4];
#pragma unroll
    for (int kb = 0; kb < 4; ++kb)
        a2[kb] = *(const short8*)(Mb + MswzB(m16, kb * 64 + hi4 * 16));
    f32x4 e4[4];
#pragma unroll
    for (int q = 0; q < 4; ++q) { e4[q].x = 0.f; e4[q].y = 0.f; e4[q].z = 0.f; e4[q].w = 0.f; }
#pragma unroll
    for (int q = 0; q < 4; ++q)
#pragma unroll
        for (int kb = 0; kb < 4; ++kb) {
            short8 b = *(const short8*)((const char*)Bp2 + ((size_t)((wq * 4 + q) * 4 + kb) * 64 + g) * 16);
            e4[q] = __builtin_amdgcn_mfma_f32_16x16x32_bf16(a2[kb], b, e4[q], 0, 0, 0);
        }
#pragma unroll
    for (int q = 0; q < 4; ++q)
#pragma unroll
        for (int r = 0; r < 4; ++r)
            G[(hi4 * 4 + r) * 260 + wq * 64 + q * 16 + m16] = e4[q][r];
    __syncthreads();

    // ---- GRU elementwise epilogue; wave wq owns nodes 4wq..4wq+3 ----
    float b_r = bih[g] + bhh[g];
    float b_z = bih[64 + g] + bhh[64 + g];
    float b_gi = bih[128 + g];
    float b_gh = bhh[128 + g];
#pragma unroll
    for (int jj = 0; jj < 4; ++jj) {
        int i = wq * 4 + jj;
        int n = n0 + i;
        float rs = G[i * 260 + g] + b_r;
        float zs = G[i * 260 + 64 + g] + b_z;
        float gi = G[i * 260 + 128 + g] + b_gi;
        float gh = G[i * 260 + 192 + g] + b_gh;
        float r = 1.f / (1.f + __expf(-rs));
        float z = 1.f / (1.f + __expf(-zs));
        float aa = gi + r * gh;
        float ex = __expf(2.f * aa);
        float nt = 1.f - 2.f / (ex + 1.f);
        float xr = Xprev[n * 64 + g];
        Xout[n * 64 + g] = (1.f - z) * nt + z * xr;
    }
}

extern "C" void kernel_launch(void* const* d_in, const int* in_sizes, int n_in,
                              void* d_out, int out_size, void* d_ws, size_t ws_size,
                              hipStream_t stream) {
    const float* h     = (const float*)d_in[0];
    const int*   ei    = (const int*)d_in[1];    // [2, E]: row0 = src, row1 = dst
    const float* eattr = (const float*)d_in[3];
    const float* lin0w = (const float*)d_in[4];
    const float* lin0b = (const float*)d_in[5];
    const float* shw   = (const float*)d_in[6];
    const float* shb   = (const float*)d_in[7];
    const float* w1    = (const float*)d_in[8];
    const float* b1    = (const float*)d_in[9];
    const float* w2    = (const float*)d_in[10];
    const float* b2    = (const float*)d_in[11];
    const float* rootw = (const float*)d_in[12];
    const float* convb = (const float*)d_in[13];
    const float* wih   = (const float*)d_in[14];
    const float* whh   = (const float*)d_in[15];
    const float* bih   = (const float*)d_in[16];
    const float* bhh   = (const float*)d_in[17];

    char* ws = (char*)d_ws;
    float* X0     = (float*)ws; ws += (size_t)N_NODES * 64 * 4;
    float* X1     = (float*)ws; ws += (size_t)N_NODES * 64 * 4;
    u16*   t_perm = (u16*)ws;   ws += (size_t)N_EDGES * 16 * 2;
    u16*   Bp1    = (u16*)ws;   ws += (size_t)73728 * 2;
    u16*   Bp2    = (u16*)ws;   ws += (size_t)32768 * 2;
    int*   cnt    = (int*)ws;   ws += (size_t)N_NODES * 4;
    int*   off    = (int*)ws;   ws += (size_t)(N_NODES + 4) * 4;
    int*   cursor = (int*)ws;   ws += (size_t)N_NODES * 4;
    float* cntf   = (float*)ws; ws += (size_t)N_NODES * 4;
    int*   pos    = (int*)ws;   ws += (size_t)N_EDGES * 4;
    int*   src_ord= (int*)ws;   ws += (size_t)N_EDGES * 4;

    hipMemsetAsync(cnt, 0, N_NODES * 4, stream);
    k_hist<<<(N_EDGES + 255) / 256, 256, 0, stream>>>(ei, cnt);
    k_scan<<<1, 1024, 0, stream>>>(cnt, off, cursor, cntf);
    k_scatter<<<(N_EDGES + 255) / 256, 256, 0, stream>>>(ei, cursor, src_ord, pos);
    k_pack<<<(73728 + 32768) / 256, 256, 0, stream>>>(w2, b2, rootw, wih, whh, Bp1, Bp2);
    k_lin0<<<N_NODES / NPB0, 256, 0, stream>>>(h, lin0w, lin0b, X0);
    k_edge_t<<<N_EDGES / 4, 256, 0, stream>>>(eattr, shw, shb, w1, b1, pos, t_perm);

    float* out = (float*)d_out;
    k_conv<<<N_NODES / NPB, 256, 0, stream>>>(X0, X1, t_perm, src_ord, off, cntf,
                                              Bp1, Bp2, convb, bih, bhh);
    k_conv<<<N_NODES / NPB, 256, 0, stream>>>(X1, out, t_perm, src_ord, off, cntf,
                                              Bp1, Bp2, convb, bih, bhh);
}

// Round 4
// 145.067 us; speedup vs baseline: 2.8684x; 1.2259x over previous
//
#include <hip/hip_runtime.h>

#define N_NODES 20000
#define N_EDGES 50000
#define NPB 16        // nodes per block in k_conv (one MFMA M-tile)
#define NPB0 8        // nodes per block in lin0 part

// fused-kernel role split (blocks)
#define HB 196        // hist: 196*256 >= 50000
#define PB 416        // pack: 416*256 = 106496 = 73728+32768
#define LB 2500       // lin0: 2500*8 = 20000
#define EB 12500      // edge_t: 12500*4 = 50000

typedef __attribute__((ext_vector_type(8))) short short8;
typedef __attribute__((ext_vector_type(4))) float f32x4;
typedef unsigned int u32;
typedef unsigned short u16;

// byte-address swizzles (keep ds_read_b128 of strided rows conflict-free)
#define SswzB(i, o) (((i) * 2304 + (o)) ^ (((i) & 7) << 4))   // S: 16 rows x 2304 B
#define MswzB(i, o) (((i) * 256 + (o)) ^ (((i) & 7) << 4))    // M|X: 16 rows x 256 B

__device__ inline u16 f2bf(float x) {            // round-to-nearest-even fp32->bf16
    u32 u = __float_as_uint(x);
    return (u16)((u + 0x7FFFu + ((u >> 16) & 1u)) >> 16);
}

// accumulate one edge: acc[k] += t[e][k] * x  (t stored bf16 x16)
__device__ inline void acc_edge(float* acc, const u16* t, float x) {
    uint4 a = *(const uint4*)t, b = *(const uint4*)(t + 8);
    u32 tw[8] = {a.x, a.y, a.z, a.w, b.x, b.y, b.z, b.w};
#pragma unroll
    for (int q = 0; q < 8; ++q) {
        acc[2 * q]     += __uint_as_float(tw[q] << 16) * x;
        acc[2 * q + 1] += __uint_as_float(tw[q] & 0xFFFF0000u) * x;
    }
}

// ---------------- fused preprocessing: hist | pack | lin0 | edge_t ----------------
__global__ __launch_bounds__(256) void k_fused(
    const int* __restrict__ ei, int* __restrict__ cnt,
    const float* __restrict__ w2, const float* __restrict__ b2, const float* __restrict__ rootw,
    const float* __restrict__ wih, const float* __restrict__ whh,
    u16* __restrict__ Bp1, u16* __restrict__ Bp2,
    const float* __restrict__ h, const float* __restrict__ lin0w, const float* __restrict__ lin0b,
    float* __restrict__ X0,
    const float* __restrict__ eattr, const float* __restrict__ sw, const float* __restrict__ sb,
    const float* __restrict__ w1, const float* __restrict__ b1, u16* __restrict__ t_arr) {
    __shared__ float sh[NPB0][64];
    int tid = threadIdx.x;
    int b = blockIdx.x;

    if (b < HB) {                       // ---- histogram of dst ----
        int e = b * 256 + tid;
        if (e < N_EDGES) atomicAdd(&cnt[ei[N_EDGES + e]], 1);
        return;
    }
    b -= HB;
    if (b < PB) {                       // ---- weight pack (bf16 MFMA B-fragments) ----
        int idx = b * 256 + tid;
        if (idx < 73728) {
            int j = idx & 7, l = (idx >> 3) & 63, rest = idx >> 9;
            int kb = rest % 36, nt = rest / 36;
            int row = kb * 32 + (l >> 4) * 8 + j;
            int col = nt * 16 + (l & 15);
            float v;
            if (row < 1024) v = w2[row * 64 + col];
            else if (row < 1088) v = b2[(row - 1024) * 64 + col];
            else v = rootw[(row - 1088) * 64 + col];
            Bp1[idx] = f2bf(v);
        } else {
            int o = idx - 73728;
            int j = o & 7, l = (o >> 3) & 63, rest = o >> 9;
            int kb = rest & 3, nt = rest >> 2;
            int k2 = kb * 32 + (l >> 4) * 8 + j;
            int c = nt * 16 + (l & 15);
            float v;
            if (k2 < 64) {
                v = (c < 192) ? wih[k2 * 192 + c] : 0.f;
            } else {
                int f = k2 - 64;
                v = (c < 128) ? whh[f * 192 + c] : ((c < 192) ? 0.f : whh[f * 192 + c - 64]);
            }
            Bp2[o] = f2bf(v);
        }
        return;
    }
    b -= PB;
    if (b < LB) {                       // ---- X0 = relu(h @ lin0_w + lin0_b) ----
        int n0 = b * NPB0;
        for (int i = tid; i < NPB0 * 64; i += 256) sh[i >> 6][i & 63] = h[n0 * 64 + i];
        __syncthreads();
        int g = tid & 63, q = tid >> 6;
        for (int j = 0; j < 2; j++) {
            int i = q * 2 + j;
            float acc = lin0b[g];
            for (int f = 0; f < 64; f++) acc += sh[i][f] * lin0w[f * 64 + g];
            X0[(n0 + i) * 64 + g] = acc > 0.f ? acc : 0.f;
        }
        return;
    }
    b -= LB;
    {                                   // ---- t[e,16] = relu(relu(ea@short)@nn1), unsorted ----
        int l = tid & 63, q = tid >> 6;
        int e = b * 4 + q;
        float a0 = eattr[e * 5 + 0], a1 = eattr[e * 5 + 1], a2 = eattr[e * 5 + 2],
              a3 = eattr[e * 5 + 3], a4 = eattr[e * 5 + 4];
        float v = sb[l] + a0 * sw[l] + a1 * sw[64 + l] + a2 * sw[128 + l] + a3 * sw[192 + l] + a4 * sw[256 + l];
        sh[q][l] = v > 0.f ? v : 0.f;
        __syncthreads();
        if (l < 16) {
            float acc = b1[l];
            for (int c = 0; c < 64; c++) acc += sh[q][c] * w1[c * 16 + l];
            float t = acc > 0.f ? acc : 0.f;
            t_arr[(size_t)e * 16 + l] = f2bf(t);
        }
    }
}

// ---------------- exclusive scan over counts (single block, shfl-based) ----------------
__global__ __launch_bounds__(1024) void k_scan(const int* __restrict__ cnt, int* __restrict__ off,
                                               int* __restrict__ cursor, float* __restrict__ cntf) {
    __shared__ int wsum[16], woff[16];
    const int PT = 20;                  // 1024*20 = 20480 >= 20000
    int tid = threadIdx.x, lane = tid & 63, w = tid >> 6;
    int base = tid * PT;
    int loc[PT];
    int sum = 0;
#pragma unroll
    for (int q = 0; q < PT; ++q) {
        int n = base + q;
        int v = (n < N_NODES) ? cnt[n] : 0;
        loc[q] = sum;
        sum += v;
    }
    int inc = sum;
#pragma unroll
    for (int d = 1; d < 64; d <<= 1) {
        int t = __shfl_up(inc, d, 64);
        if (lane >= d) inc += t;
    }
    if (lane == 63) wsum[w] = inc;
    __syncthreads();
    if (w == 0 && lane < 16) {
        int v = wsum[lane];
        int iv = v;
#pragma unroll
        for (int d = 1; d < 16; d <<= 1) {
            int t = __shfl_up(iv, d, 64);
            if (lane >= d) iv += t;
        }
        woff[lane] = iv - v;
        if (lane == 15) wsum[15] = iv;   // grand total
    }
    __syncthreads();
    int excl = woff[w] + (inc - sum);
#pragma unroll
    for (int q = 0; q < PT; ++q) {
        int n = base + q;
        if (n < N_NODES) {
            int o = excl + loc[q];
            int v = ((q + 1 < PT) ? loc[q + 1] : sum) - loc[q];
            off[n] = o;
            cursor[n] = o;
            cntf[n] = v > 0 ? (float)v : 1.0f;
        }
    }
    if (tid == 0) off[N_NODES] = wsum[15];
}

// ---------------- scatter: grouped-by-dst (src, edge) pairs ----------------
__global__ __launch_bounds__(256) void k_scatter(const int* __restrict__ ei, int* __restrict__ cursor,
                                                 int2* __restrict__ edata) {
    int e = blockIdx.x * 256 + threadIdx.x;
    if (e < N_EDGES) {
        int d = ei[N_EDGES + e];
        int p = atomicAdd(&cursor[d], 1);
        edata[p] = make_int2(ei[e], e);
    }
}

// ---------------- fused conv + GRU (MFMA), one iteration ----------------
__global__ __launch_bounds__(256, 4) void k_conv(
    const float* __restrict__ Xprev, float* __restrict__ Xout,
    const u16* __restrict__ t_arr, const int2* __restrict__ edata,
    const int* __restrict__ off, const float* __restrict__ cntf,
    const u16* __restrict__ Bp1, const u16* __restrict__ Bp2,
    const float* __restrict__ convb,
    const float* __restrict__ bih, const float* __restrict__ bhh) {
    __shared__ __align__(16) char smem[40960];
    char* Sb = smem;                 // S: 16 nodes x 1152 bf16 (swizzled)   [36864 B]
    char* Mb = smem + 36864;         // [M|X]: 16 nodes x 128 bf16 (swizzled) [4096 B]
    float* G = (float*)smem;         // gate sums: 16 x 260 f32, aliases S

    int tid = threadIdx.x;
    int g = tid & 63;
    int wq = tid >> 6;
    int m16 = g & 15, hi4 = g >> 4;
    int n0 = blockIdx.x * NPB;

    float xr4[4];

    // ---- phase 1: edge gather (4-wide batches for MLP) -> S bf16 ----
    for (int jj = 0; jj < 4; ++jj) {
        int i = wq * 4 + jj;
        int n = n0 + i;
        float xr = Xprev[n * 64 + g];
        xr4[jj] = xr;
        float acc[16];
#pragma unroll
        for (int k = 0; k < 16; ++k) acc[k] = 0.f;
        float sx = 0.f;
        int e0 = off[n], e1 = off[n + 1];
        for (int p = e0; p < e1; p += 4) {
            int m = e1 - p;    // >= 1
            int2 ed0 = edata[p];
            int2 ed1 = edata[m > 1 ? p + 1 : p];
            int2 ed2 = edata[m > 2 ? p + 2 : p];
            int2 ed3 = edata[m > 3 ? p + 3 : p];
            float x0 = Xprev[ed0.x * 64 + g];
            float x1 = m > 1 ? Xprev[ed1.x * 64 + g] : 0.f;
            float x2 = m > 2 ? Xprev[ed2.x * 64 + g] : 0.f;
            float x3 = m > 3 ? Xprev[ed3.x * 64 + g] : 0.f;
            acc_edge(acc, t_arr + (size_t)ed0.y * 16, x0);
            acc_edge(acc, t_arr + (size_t)ed1.y * 16, x1);
            acc_edge(acc, t_arr + (size_t)ed2.y * 16, x2);
            acc_edge(acc, t_arr + (size_t)ed3.y * 16, x3);
            sx += x0 + x1 + x2 + x3;
        }
        float ic = 1.0f / cntf[n];
#pragma unroll
        for (int k = 0; k < 16; ++k)
            *(u16*)(Sb + SswzB(i, k * 128 + g * 2)) = f2bf(acc[k] * ic);
        *(u16*)(Sb + SswzB(i, 2048 + g * 2)) = f2bf(sx * ic);   // nn2_b rows
        *(u16*)(Sb + SswzB(i, 2176 + g * 2)) = f2bf(xr);        // root rows
        *(u16*)(Mb + MswzB(i, 128 + g * 2)) = f2bf(xr);         // X half of A2
    }
    __syncthreads();

    // ---- GEMM1: [16 x 1152] @ [1152 x 64] ; wave wq owns feature tile wq ----
    f32x4 d = {0.f, 0.f, 0.f, 0.f};
#pragma unroll
    for (int kb = 0; kb < 36; ++kb) {
        short8 a = *(const short8*)(Sb + SswzB(m16, kb * 64 + hi4 * 16));
        short8 b = *(const short8*)((const char*)Bp1 + ((size_t)(wq * 36 + kb) * 64 + g) * 16);
        d = __builtin_amdgcn_mfma_f32_16x16x32_bf16(a, b, d, 0, 0, 0);
    }
    {
        float cb = convb[wq * 16 + m16];
#pragma unroll
        for (int r = 0; r < 4; ++r) {
            float m = d[r] + cb;
            m = m > 0.f ? m : 0.f;       // relu -> M
            int row = hi4 * 4 + r, col = wq * 16 + m16;
            // cross-lane layout: lane holding (row,col) differs from writer; use b16 store
            *(u16*)(Mb + MswzB(row, col * 2)) = f2bf(m);
        }
    }
    __syncthreads();   // M complete; all S reads done (G may alias S now)

    // ---- GEMM2: [16 x 128] @ [128 x 256] ; wave wq owns gate wq ----
    short8 a2[4];
#pragma unroll
    for (int kb = 0; kb < 4; ++kb)
        a2[kb] = *(const short8*)(Mb + MswzB(m16, kb * 64 + hi4 * 16));
    f32x4 e4[4];
#pragma unroll
    for (int q = 0; q < 4; ++q) { e4[q].x = 0.f; e4[q].y = 0.f; e4[q].z = 0.f; e4[q].w = 0.f; }
#pragma unroll
    for (int q = 0; q < 4; ++q)
#pragma unroll
        for (int kb = 0; kb < 4; ++kb) {
            short8 b = *(const short8*)((const char*)Bp2 + ((size_t)((wq * 4 + q) * 4 + kb) * 64 + g) * 16);
            e4[q] = __builtin_amdgcn_mfma_f32_16x16x32_bf16(a2[kb], b, e4[q], 0, 0, 0);
        }
#pragma unroll
    for (int q = 0; q < 4; ++q)
#pragma unroll
        for (int r = 0; r < 4; ++r)
            G[(hi4 * 4 + r) * 260 + wq * 64 + q * 16 + m16] = e4[q][r];
    __syncthreads();

    // ---- GRU elementwise epilogue; wave wq owns nodes 4wq..4wq+3 ----
    float b_r = bih[g] + bhh[g];
    float b_z = bih[64 + g] + bhh[64 + g];
    float b_gi = bih[128 + g];
    float b_gh = bhh[128 + g];
#pragma unroll
    for (int jj = 0; jj < 4; ++jj) {
        int i = wq * 4 + jj;
        int n = n0 + i;
        float rs = G[i * 260 + g] + b_r;
        float zs = G[i * 260 + 64 + g] + b_z;
        float gi = G[i * 260 + 128 + g] + b_gi;
        float gh = G[i * 260 + 192 + g] + b_gh;
        float r = 1.f / (1.f + __expf(-rs));
        float z = 1.f / (1.f + __expf(-zs));
        float aa = gi + r * gh;
        float ex = __expf(2.f * aa);
        float nt = 1.f - 2.f / (ex + 1.f);
        Xout[n * 64 + g] = (1.f - z) * nt + z * xr4[jj];
    }
}

extern "C" void kernel_launch(void* const* d_in, const int* in_sizes, int n_in,
                              void* d_out, int out_size, void* d_ws, size_t ws_size,
                              hipStream_t stream) {
    const float* h     = (const float*)d_in[0];
    const int*   ei    = (const int*)d_in[1];    // [2, E]: row0 = src, row1 = dst
    const float* eattr = (const float*)d_in[3];
    const float* lin0w = (const float*)d_in[4];
    const float* lin0b = (const float*)d_in[5];
    const float* shw   = (const float*)d_in[6];
    const float* shb   = (const float*)d_in[7];
    const float* w1    = (const float*)d_in[8];
    const float* b1    = (const float*)d_in[9];
    const float* w2    = (const float*)d_in[10];
    const float* b2    = (const float*)d_in[11];
    const float* rootw = (const float*)d_in[12];
    const float* convb = (const float*)d_in[13];
    const float* wih   = (const float*)d_in[14];
    const float* whh   = (const float*)d_in[15];
    const float* bih   = (const float*)d_in[16];
    const float* bhh   = (const float*)d_in[17];

    char* ws = (char*)d_ws;
    float* X0     = (float*)ws; ws += (size_t)N_NODES * 64 * 4;
    float* X1     = (float*)ws; ws += (size_t)N_NODES * 64 * 4;
    u16*   t_arr  = (u16*)ws;   ws += (size_t)N_EDGES * 16 * 2;
    u16*   Bp1    = (u16*)ws;   ws += (size_t)73728 * 2;
    u16*   Bp2    = (u16*)ws;   ws += (size_t)32768 * 2;
    int*   cnt    = (int*)ws;   ws += (size_t)N_NODES * 4;
    int*   off    = (int*)ws;   ws += (size_t)(N_NODES + 4) * 4;
    int*   cursor = (int*)ws;   ws += (size_t)N_NODES * 4;
    float* cntf   = (float*)ws; ws += (size_t)N_NODES * 4;
    int2*  edata  = (int2*)ws;  ws += (size_t)N_EDGES * 8;

    hipMemsetAsync(cnt, 0, N_NODES * 4, stream);
    k_fused<<<HB + PB + LB + EB, 256, 0, stream>>>(ei, cnt, w2, b2, rootw, wih, whh,
                                                   Bp1, Bp2, h, lin0w, lin0b, X0,
                                                   eattr, shw, shb, w1, b1, t_arr);
    k_scan<<<1, 1024, 0, stream>>>(cnt, off, cursor, cntf);
    k_scatter<<<(N_EDGES + 255) / 256, 256, 0, stream>>>(ei, cursor, edata);

    float* out = (float*)d_out;
    k_conv<<<N_NODES / NPB, 256, 0, stream>>>(X0, X1, t_arr, edata, off, cntf,
                                              Bp1, Bp2, convb, bih, bhh);
    k_conv<<<N_NODES / NPB, 256, 0, stream>>>(X1, out, t_arr, edata, off, cntf,
                                              Bp1, Bp2, convb, bih, bhh);
}

// Round 5
// 129.926 us; speedup vs baseline: 3.2027x; 1.1165x over previous
//
#include <hip/hip_runtime.h>

#define N_NODES 20000
#define N_EDGES 50000
#define NPB 16        // nodes per block in k_conv (one MFMA M-tile)

// k_pre role split (blocks)
#define ZB 79         // zero cnt: 79*256 = 20224 >= 20000
#define PB 416        // pack: 416*256 = 106496 = 73728+32768
// k_fused2 role split (blocks)
#define HB 196        // hist: 196*256 >= 50000
#define LB 1250       // lin0: 1250*16 = 20000
#define EB 3125       // edge_t: 3125*16 = 50000

typedef __attribute__((ext_vector_type(8))) short short8;
typedef __attribute__((ext_vector_type(4))) float f32x4;
typedef unsigned int u32;
typedef unsigned short u16;

// byte-address swizzles (keep ds_read_b128 of strided rows conflict-free)
#define SswzB(i, o) (((i) * 2304 + (o)) ^ (((i) & 7) << 4))   // S: 16 rows x 2304 B
#define MswzB(i, o) (((i) * 256 + (o)) ^ (((i) & 7) << 4))    // M|X: 16 rows x 256 B

__device__ inline u16 f2bf(float x) {            // round-to-nearest-even fp32->bf16
    u32 u = __float_as_uint(x);
    return (u16)((u + 0x7FFFu + ((u >> 16) & 1u)) >> 16);
}

// accumulate one edge: acc[k] += t[e][k] * x  (t stored bf16 x16)
__device__ inline void acc_edge(float* acc, const u16* t, float x) {
    uint4 a = *(const uint4*)t, b = *(const uint4*)(t + 8);
    u32 tw[8] = {a.x, a.y, a.z, a.w, b.x, b.y, b.z, b.w};
#pragma unroll
    for (int q = 0; q < 8; ++q) {
        acc[2 * q]     += __uint_as_float(tw[q] << 16) * x;
        acc[2 * q + 1] += __uint_as_float(tw[q] & 0xFFFF0000u) * x;
    }
}

// ---------------- k_pre: zero cnt | pack weights (replaces hipMemsetAsync) ----------------
__global__ __launch_bounds__(256) void k_pre(
    int* __restrict__ cnt,
    const float* __restrict__ w2, const float* __restrict__ b2, const float* __restrict__ rootw,
    const float* __restrict__ wih, const float* __restrict__ whh,
    u16* __restrict__ Bp1, u16* __restrict__ Bp2) {
    int tid = threadIdx.x;
    int b = blockIdx.x;
    if (b < ZB) {                       // ---- zero dst-degree counters ----
        int n = b * 256 + tid;
        if (n < N_NODES) cnt[n] = 0;
        return;
    }
    b -= ZB;
    {                                   // ---- weight pack (bf16 MFMA B-fragments) ----
        int idx = b * 256 + tid;
        if (idx < 73728) {
            int j = idx & 7, l = (idx >> 3) & 63, rest = idx >> 9;
            int kb = rest % 36, nt = rest / 36;
            int row = kb * 32 + (l >> 4) * 8 + j;
            int col = nt * 16 + (l & 15);
            float v;
            if (row < 1024) v = w2[row * 64 + col];
            else if (row < 1088) v = b2[(row - 1024) * 64 + col];
            else v = rootw[(row - 1088) * 64 + col];
            Bp1[idx] = f2bf(v);
        } else {
            int o = idx - 73728;
            int j = o & 7, l = (o >> 3) & 63, rest = o >> 9;
            int kb = rest & 3, nt = rest >> 2;
            int k2 = kb * 32 + (l >> 4) * 8 + j;
            int c = nt * 16 + (l & 15);
            float v;
            if (k2 < 64) {
                v = (c < 192) ? wih[k2 * 192 + c] : 0.f;
            } else {
                int f = k2 - 64;
                v = (c < 128) ? whh[f * 192 + c] : ((c < 192) ? 0.f : whh[f * 192 + c - 64]);
            }
            Bp2[o] = f2bf(v);
        }
    }
}

// ---------------- fused preprocessing: hist | lin0 | edge_t ----------------
__global__ __launch_bounds__(256) void k_fused2(
    const int* __restrict__ ei, int* __restrict__ cnt,
    const float* __restrict__ h, const float* __restrict__ lin0w, const float* __restrict__ lin0b,
    float* __restrict__ X0,
    const float* __restrict__ eattr, const float* __restrict__ sw, const float* __restrict__ sb,
    const float* __restrict__ w1, const float* __restrict__ b1, u16* __restrict__ t_arr) {
    __shared__ float sh[16][64];
    int tid = threadIdx.x;
    int b = blockIdx.x;

    if (b < HB) {                       // ---- histogram of dst ----
        int e = b * 256 + tid;
        if (e < N_EDGES) atomicAdd(&cnt[ei[N_EDGES + e]], 1);
        return;
    }
    b -= HB;
    int g = tid & 63, q = tid >> 6;
    if (b < LB) {                       // ---- X0 = relu(h @ lin0_w + lin0_b), 16 nodes ----
        int n0 = b * 16;
        for (int i = tid; i < 16 * 64; i += 256) sh[i >> 6][i & 63] = h[n0 * 64 + i];
        __syncthreads();
        for (int j = 0; j < 4; j++) {
            int i = q * 4 + j;
            float acc = lin0b[g];
            for (int f = 0; f < 64; f++) acc += sh[i][f] * lin0w[f * 64 + g];
            X0[(n0 + i) * 64 + g] = acc > 0.f ? acc : 0.f;
        }
        return;
    }
    b -= LB;
    {                                   // ---- t[e,16] = relu(relu(ea@short)@nn1), 16 edges ----
        int e0 = b * 16;
#pragma unroll
        for (int j = 0; j < 4; j++) {
            int r = q * 4 + j;
            int e = e0 + r;
            float a0 = eattr[e * 5 + 0], a1 = eattr[e * 5 + 1], a2 = eattr[e * 5 + 2],
                  a3 = eattr[e * 5 + 3], a4 = eattr[e * 5 + 4];
            float v = sb[g] + a0 * sw[g] + a1 * sw[64 + g] + a2 * sw[128 + g]
                    + a3 * sw[192 + g] + a4 * sw[256 + g];
            sh[r][g] = v > 0.f ? v : 0.f;
        }
        __syncthreads();
        if (g < 16) {
#pragma unroll
            for (int j = 0; j < 4; j++) {
                int r = q * 4 + j;
                float acc = b1[g];
                for (int c = 0; c < 64; c++) acc += sh[r][c] * w1[c * 16 + g];
                float t = acc > 0.f ? acc : 0.f;
                t_arr[(size_t)(e0 + r) * 16 + g] = f2bf(t);
            }
        }
    }
}

// ---------------- exclusive scan over counts (single block, shfl-based) ----------------
__global__ __launch_bounds__(1024) void k_scan(const int* __restrict__ cnt, int* __restrict__ off,
                                               int* __restrict__ cursor, float* __restrict__ cntf) {
    __shared__ int wsum[16], woff[16];
    const int PT = 20;                  // 1024*20 = 20480 >= 20000
    int tid = threadIdx.x, lane = tid & 63, w = tid >> 6;
    int base = tid * PT;
    int loc[PT];
    int sum = 0;
#pragma unroll
    for (int q = 0; q < PT; ++q) {
        int n = base + q;
        int v = (n < N_NODES) ? cnt[n] : 0;
        loc[q] = sum;
        sum += v;
    }
    int inc = sum;
#pragma unroll
    for (int d = 1; d < 64; d <<= 1) {
        int t = __shfl_up(inc, d, 64);
        if (lane >= d) inc += t;
    }
    if (lane == 63) wsum[w] = inc;
    __syncthreads();
    if (w == 0 && lane < 16) {
        int v = wsum[lane];
        int iv = v;
#pragma unroll
        for (int d = 1; d < 16; d <<= 1) {
            int t = __shfl_up(iv, d, 64);
            if (lane >= d) iv += t;
        }
        woff[lane] = iv - v;
        if (lane == 15) wsum[15] = iv;   // grand total
    }
    __syncthreads();
    int excl = woff[w] + (inc - sum);
#pragma unroll
    for (int q = 0; q < PT; ++q) {
        int n = base + q;
        if (n < N_NODES) {
            int o = excl + loc[q];
            int v = ((q + 1 < PT) ? loc[q + 1] : sum) - loc[q];
            off[n] = o;
            cursor[n] = o;
            cntf[n] = v > 0 ? (float)v : 1.0f;
        }
    }
    if (tid == 0) off[N_NODES] = wsum[15];
}

// ---------------- scatter: grouped-by-dst (src, edge) pairs ----------------
__global__ __launch_bounds__(256) void k_scatter(const int* __restrict__ ei, int* __restrict__ cursor,
                                                 int2* __restrict__ edata) {
    int e = blockIdx.x * 256 + threadIdx.x;
    if (e < N_EDGES) {
        int d = ei[N_EDGES + e];
        int p = atomicAdd(&cursor[d], 1);
        edata[p] = make_int2(ei[e], e);
    }
}

// ---------------- fused conv + GRU (MFMA), one iteration ----------------
__global__ __launch_bounds__(256, 4) void k_conv(
    const float* __restrict__ Xprev, float* __restrict__ Xout,
    const u16* __restrict__ t_arr, const int2* __restrict__ edata,
    const int* __restrict__ off, const float* __restrict__ cntf,
    const u16* __restrict__ Bp1, const u16* __restrict__ Bp2,
    const float* __restrict__ convb,
    const float* __restrict__ bih, const float* __restrict__ bhh) {
    __shared__ __align__(16) char smem[40960];
    char* Sb = smem;                 // S: 16 nodes x 1152 bf16 (swizzled)   [36864 B]
    char* Mb = smem + 36864;         // [M|X]: 16 nodes x 128 bf16 (swizzled) [4096 B]
    float* G = (float*)smem;         // gate sums: 16 x 260 f32, aliases S

    int tid = threadIdx.x;
    int g = tid & 63;
    int wq = tid >> 6;
    int m16 = g & 15, hi4 = g >> 4;
    int n0 = blockIdx.x * NPB;

    // ---- hoisted per-node metadata: one latency round for all 4 nodes ----
    int e0v[4], e1v[4];
    float xr4[4], ic4[4];
#pragma unroll
    for (int jj = 0; jj < 4; ++jj) {
        int n = n0 + wq * 4 + jj;
        e0v[jj] = __builtin_amdgcn_readfirstlane(off[n]);
        e1v[jj] = __builtin_amdgcn_readfirstlane(off[n + 1]);
        xr4[jj] = Xprev[n * 64 + g];
        ic4[jj] = 1.0f / cntf[n];
    }

    // ---- phase 1: edge gather (4-wide batches for MLP) -> S bf16 ----
    for (int jj = 0; jj < 4; ++jj) {
        int i = wq * 4 + jj;
        float acc[16];
#pragma unroll
        for (int k = 0; k < 16; ++k) acc[k] = 0.f;
        float sx = 0.f;
        int e0 = e0v[jj], e1 = e1v[jj];
        for (int p = e0; p < e1; p += 4) {
            int m = e1 - p;    // >= 1
            int2 ed0 = edata[p];
            int2 ed1 = edata[m > 1 ? p + 1 : p];
            int2 ed2 = edata[m > 2 ? p + 2 : p];
            int2 ed3 = edata[m > 3 ? p + 3 : p];
            float x0 = Xprev[ed0.x * 64 + g];
            float x1 = m > 1 ? Xprev[ed1.x * 64 + g] : 0.f;
            float x2 = m > 2 ? Xprev[ed2.x * 64 + g] : 0.f;
            float x3 = m > 3 ? Xprev[ed3.x * 64 + g] : 0.f;
            acc_edge(acc, t_arr + (size_t)ed0.y * 16, x0);
            acc_edge(acc, t_arr + (size_t)ed1.y * 16, x1);
            acc_edge(acc, t_arr + (size_t)ed2.y * 16, x2);
            acc_edge(acc, t_arr + (size_t)ed3.y * 16, x3);
            sx += x0 + x1 + x2 + x3;
        }
        float ic = ic4[jj];
#pragma unroll
        for (int k = 0; k < 16; ++k)
            *(u16*)(Sb + SswzB(i, k * 128 + g * 2)) = f2bf(acc[k] * ic);
        *(u16*)(Sb + SswzB(i, 2048 + g * 2)) = f2bf(sx * ic);   // nn2_b rows
        *(u16*)(Sb + SswzB(i, 2176 + g * 2)) = f2bf(xr4[jj]);   // root rows
        *(u16*)(Mb + MswzB(i, 128 + g * 2)) = f2bf(xr4[jj]);    // X half of A2
    }
    __syncthreads();

    // ---- GEMM1: [16 x 1152] @ [1152 x 64] ; wave wq owns feature tile wq ----
    f32x4 d = {0.f, 0.f, 0.f, 0.f};
#pragma unroll
    for (int kb = 0; kb < 36; ++kb) {
        short8 a = *(const short8*)(Sb + SswzB(m16, kb * 64 + hi4 * 16));
        short8 b = *(const short8*)((const char*)Bp1 + ((size_t)(wq * 36 + kb) * 64 + g) * 16);
        d = __builtin_amdgcn_mfma_f32_16x16x32_bf16(a, b, d, 0, 0, 0);
    }
    {
        float cb = convb[wq * 16 + m16];
#pragma unroll
        for (int r = 0; r < 4; ++r) {
            float m = d[r] + cb;
            m = m > 0.f ? m : 0.f;       // relu -> M
            int row = hi4 * 4 + r, col = wq * 16 + m16;
            *(u16*)(Mb + MswzB(row, col * 2)) = f2bf(m);
        }
    }
    __syncthreads();   // M complete; all S reads done (G may alias S now)

    // ---- GEMM2: [16 x 128] @ [128 x 256] ; wave wq owns gate wq ----
    short8 a2[4];
#pragma unroll
    for (int kb = 0; kb < 4; ++kb)
        a2[kb] = *(const short8*)(Mb + MswzB(m16, kb * 64 + hi4 * 16));
    f32x4 e4[4];
#pragma unroll
    for (int q = 0; q < 4; ++q) { e4[q].x = 0.f; e4[q].y = 0.f; e4[q].z = 0.f; e4[q].w = 0.f; }
#pragma unroll
    for (int q = 0; q < 4; ++q)
#pragma unroll
        for (int kb = 0; kb < 4; ++kb) {
            short8 b = *(const short8*)((const char*)Bp2 + ((size_t)((wq * 4 + q) * 4 + kb) * 64 + g) * 16);
            e4[q] = __builtin_amdgcn_mfma_f32_16x16x32_bf16(a2[kb], b, e4[q], 0, 0, 0);
        }
#pragma unroll
    for (int q = 0; q < 4; ++q)
#pragma unroll
        for (int r = 0; r < 4; ++r)
            G[(hi4 * 4 + r) * 260 + wq * 64 + q * 16 + m16] = e4[q][r];
    __syncthreads();

    // ---- GRU elementwise epilogue; wave wq owns nodes 4wq..4wq+3 ----
    float b_r = bih[g] + bhh[g];
    float b_z = bih[64 + g] + bhh[64 + g];
    float b_gi = bih[128 + g];
    float b_gh = bhh[128 + g];
#pragma unroll
    for (int jj = 0; jj < 4; ++jj) {
        int i = wq * 4 + jj;
        int n = n0 + i;
        float rs = G[i * 260 + g] + b_r;
        float zs = G[i * 260 + 64 + g] + b_z;
        float gi = G[i * 260 + 128 + g] + b_gi;
        float gh = G[i * 260 + 192 + g] + b_gh;
        float r = 1.f / (1.f + __expf(-rs));
        float z = 1.f / (1.f + __expf(-zs));
        float aa = gi + r * gh;
        float ex = __expf(2.f * aa);
        float nt = 1.f - 2.f / (ex + 1.f);
        Xout[n * 64 + g] = (1.f - z) * nt + z * xr4[jj];
    }
}

extern "C" void kernel_launch(void* const* d_in, const int* in_sizes, int n_in,
                              void* d_out, int out_size, void* d_ws, size_t ws_size,
                              hipStream_t stream) {
    const float* h     = (const float*)d_in[0];
    const int*   ei    = (const int*)d_in[1];    // [2, E]: row0 = src, row1 = dst
    const float* eattr = (const float*)d_in[3];
    const float* lin0w = (const float*)d_in[4];
    const float* lin0b = (const float*)d_in[5];
    const float* shw   = (const float*)d_in[6];
    const float* shb   = (const float*)d_in[7];
    const float* w1    = (const float*)d_in[8];
    const float* b1    = (const float*)d_in[9];
    const float* w2    = (const float*)d_in[10];
    const float* b2    = (const float*)d_in[11];
    const float* rootw = (const float*)d_in[12];
    const float* convb = (const float*)d_in[13];
    const float* wih   = (const float*)d_in[14];
    const float* whh   = (const float*)d_in[15];
    const float* bih   = (const float*)d_in[16];
    const float* bhh   = (const float*)d_in[17];

    char* ws = (char*)d_ws;
    float* X0     = (float*)ws; ws += (size_t)N_NODES * 64 * 4;
    float* X1     = (float*)ws; ws += (size_t)N_NODES * 64 * 4;
    u16*   t_arr  = (u16*)ws;   ws += (size_t)N_EDGES * 16 * 2;
    u16*   Bp1    = (u16*)ws;   ws += (size_t)73728 * 2;
    u16*   Bp2    = (u16*)ws;   ws += (size_t)32768 * 2;
    int*   cnt    = (int*)ws;   ws += (size_t)N_NODES * 4;
    int*   off    = (int*)ws;   ws += (size_t)(N_NODES + 4) * 4;
    int*   cursor = (int*)ws;   ws += (size_t)N_NODES * 4;
    float* cntf   = (float*)ws; ws += (size_t)N_NODES * 4;
    int2*  edata  = (int2*)ws;  ws += (size_t)N_EDGES * 8;

    k_pre<<<ZB + PB, 256, 0, stream>>>(cnt, w2, b2, rootw, wih, whh, Bp1, Bp2);
    k_fused2<<<HB + LB + EB, 256, 0, stream>>>(ei, cnt, h, lin0w, lin0b, X0,
                                               eattr, shw, shb, w1, b1, t_arr);
    k_scan<<<1, 1024, 0, stream>>>(cnt, off, cursor, cntf);
    k_scatter<<<(N_EDGES + 255) / 256, 256, 0, stream>>>(ei, cursor, edata);

    float* out = (float*)d_out;
    k_conv<<<N_NODES / NPB, 256, 0, stream>>>(X0, X1, t_arr, edata, off, cntf,
                                              Bp1, Bp2, convb, bih, bhh);
    k_conv<<<N_NODES / NPB, 256, 0, stream>>>(X1, out, t_arr, edata, off, cntf,
                                              Bp1, Bp2, convb, bih, bhh);
}